// Round 7
// baseline (334.269 us; speedup 1.0000x reference)
//
#include <hip/hip_runtime.h>

typedef _Float16 f16;
typedef f16 f16x4 __attribute__((ext_vector_type(4)));
typedef f16 f16x8 __attribute__((ext_vector_type(8)));
typedef float f32x4 __attribute__((ext_vector_type(4)));

#define LGKM0 do { asm volatile("s_waitcnt lgkmcnt(0)" ::: "memory"); __builtin_amdgcn_sched_barrier(0); } while (0)
#define VMW(n) asm volatile("s_waitcnt vmcnt(" #n ")" ::: "memory")

// ---------------- cast fp32 -> fp16 (vectorized) ----------------
__global__ void k_cast(const float* __restrict__ src, f16* __restrict__ dst, int n4) {
    int i = blockIdx.x * 256 + threadIdx.x;
    if (i < n4) {
        f32x4 v = *(const f32x4*)(src + (size_t)i * 4);
        f16x4 h = { (f16)v[0], (f16)v[1], (f16)v[2], (f16)v[3] };
        *(f16x4*)(dst + (size_t)i * 4) = h;
    }
}

// ---------------- transpose + cast: src[R][C] f32 -> dst[C][R] f16 ----------------
__global__ __launch_bounds__(256) void k_transpose_cast(const float* __restrict__ src,
                                                        f16* __restrict__ dst, int R, int C) {
    __shared__ float tile[32 * 33];
    int tx = threadIdx.x & 31, ty = threadIdx.x >> 5;
    int c0 = blockIdx.x * 32, r0 = blockIdx.y * 32;
#pragma unroll
    for (int i = 0; i < 4; ++i) {
        int r = ty + i * 8;
        tile[r * 33 + tx] = src[(size_t)(r0 + r) * C + c0 + tx];
    }
    __syncthreads();
#pragma unroll
    for (int i = 0; i < 4; ++i) {
        int rr = ty + i * 8;
        dst[(size_t)(c0 + rr) * R + r0 + tx] = (f16)tile[tx * 33 + rr];
    }
}

// ---------------- videos GEMM, 8-phase schedule ----------------
// Ch[6400][1024] = f16(A[6400][4096] @ Bt[1024][4096]^T + bias)
// BM=256 BN=128 BK=64; 512 thr, 8 waves 4x2, wave-tile 64x64.
// LDS 2 x (A 32KB [kh][256][4ch] + B 16KB [kh][128][4ch]); chunk = k-half (3 loads).
// 4 phases/K-tile; counted vmcnt(6) steady state; swizzle cc ^= (r&3)^((r>>2)&3)
// on BOTH global source and ds_read (rule #21).
__global__ __launch_bounds__(512, 2) void k_gemm2(const f16* __restrict__ A, const f16* __restrict__ Bt,
                                                  const float* __restrict__ bias, f16* __restrict__ Ch) {
    constexpr int K = 4096, N = 1024, NT = 64;
    constexpr int BUFB = 49152;
    __shared__ __attribute__((aligned(16))) char smem[2 * BUFB];
    const int tid = threadIdx.x;
    const int lane = tid & 63, wave = tid >> 6;
    const int wm = wave >> 1, wn = wave & 1;  // 4 x 2 waves
    const int lr = lane & 15, lq = lane >> 4;
    const int orig = blockIdx.x;              // bijective XCD swizzle, 200 = 8*25
    const int wg = (orig & 7) * 25 + (orig >> 3);
    const int mt = wg >> 3, nt = wg & 7;
    const int m0 = mt * 256, n0 = nt * 128;

    auto sw = [](int r) { return (r & 3) ^ ((r >> 2) & 3); };
    // staging: thread -> (row, chunk) with pre-swizzled global column
    const int rA0 = tid >> 2, rA1 = (tid + 512) >> 2, rB = tid >> 2;
    const int scA0 = (((tid) & 3) ^ sw(rA0)) * 8;
    const int scA1 = (((tid + 512) & 3) ^ sw(rA1)) * 8;
    const int scB = ((tid & 3) ^ sw(rB)) * 8;
    const f16* gA0 = A + (size_t)(m0 + rA0) * K + scA0;
    const f16* gA1 = A + (size_t)(m0 + rA1) * K + scA1;
    const f16* gB = Bt + (size_t)(n0 + rB) * K + scB;

    auto issue = [&](int c, int t, int h) {
        const int go = t * 64 + h * 32;
        char* base = smem + c * BUFB;
        __builtin_amdgcn_global_load_lds(
            (const __attribute__((address_space(1))) void*)(gA0 + go),
            (__attribute__((address_space(3))) void*)(base + h * 16384 + tid * 16), 16, 0, 0);
        __builtin_amdgcn_global_load_lds(
            (const __attribute__((address_space(1))) void*)(gA1 + go),
            (__attribute__((address_space(3))) void*)(base + h * 16384 + 8192 + tid * 16), 16, 0, 0);
        __builtin_amdgcn_global_load_lds(
            (const __attribute__((address_space(1))) void*)(gB + go),
            (__attribute__((address_space(3))) void*)(base + 32768 + h * 8192 + tid * 16), 16, 0, 0);
    };

    // ds_read byte offsets (swizzled)
    int aoff[4], boff[4];
#pragma unroll
    for (int m = 0; m < 4; ++m) {
        int r = wm * 64 + m * 16 + lr;
        aoff[m] = r * 64 + ((lq ^ sw(r)) * 16);
    }
#pragma unroll
    for (int n = 0; n < 4; ++n) {
        int r = wn * 64 + n * 16 + lr;
        boff[n] = r * 64 + ((lq ^ sw(r)) * 16);
    }

    f32x4 acc[4][4] = {};

    issue(0, 0, 0);
    issue(0, 0, 1);
    issue(1, 1, 0);
    VMW(6);  // Q(0,0) landed; Q(0,1)/Q(1,0) in flight
    __builtin_amdgcn_s_barrier();

    for (int t = 0; t < NT; ++t) {
        const int c = t & 1;
        const char* ab = smem + c * BUFB;
        const char* bb = ab + 32768;
        f16x8 a0, a1, a2, a3, b0, b1;
        // ---- ph0: ks0, n0/n1 ----
        a0 = *(const f16x8*)(ab + aoff[0]);
        a1 = *(const f16x8*)(ab + aoff[1]);
        a2 = *(const f16x8*)(ab + aoff[2]);
        a3 = *(const f16x8*)(ab + aoff[3]);
        b0 = *(const f16x8*)(bb + boff[0]);
        b1 = *(const f16x8*)(bb + boff[1]);
        if (t + 1 < NT) issue(c ^ 1, t + 1, 1);
        __builtin_amdgcn_s_barrier();
        LGKM0;
        __builtin_amdgcn_s_setprio(1);
        acc[0][0] = __builtin_amdgcn_mfma_f32_16x16x32_f16(a0, b0, acc[0][0], 0, 0, 0);
        acc[1][0] = __builtin_amdgcn_mfma_f32_16x16x32_f16(a1, b0, acc[1][0], 0, 0, 0);
        acc[2][0] = __builtin_amdgcn_mfma_f32_16x16x32_f16(a2, b0, acc[2][0], 0, 0, 0);
        acc[3][0] = __builtin_amdgcn_mfma_f32_16x16x32_f16(a3, b0, acc[3][0], 0, 0, 0);
        acc[0][1] = __builtin_amdgcn_mfma_f32_16x16x32_f16(a0, b1, acc[0][1], 0, 0, 0);
        acc[1][1] = __builtin_amdgcn_mfma_f32_16x16x32_f16(a1, b1, acc[1][1], 0, 0, 0);
        acc[2][1] = __builtin_amdgcn_mfma_f32_16x16x32_f16(a2, b1, acc[2][1], 0, 0, 0);
        acc[3][1] = __builtin_amdgcn_mfma_f32_16x16x32_f16(a3, b1, acc[3][1], 0, 0, 0);
        __builtin_amdgcn_s_setprio(0);
        __builtin_amdgcn_s_barrier();
        // ---- ph1: ks0, n2/n3 ----
        b0 = *(const f16x8*)(bb + boff[2]);
        b1 = *(const f16x8*)(bb + boff[3]);
        __builtin_amdgcn_s_barrier();
        LGKM0;
        __builtin_amdgcn_s_setprio(1);
        acc[0][2] = __builtin_amdgcn_mfma_f32_16x16x32_f16(a0, b0, acc[0][2], 0, 0, 0);
        acc[1][2] = __builtin_amdgcn_mfma_f32_16x16x32_f16(a1, b0, acc[1][2], 0, 0, 0);
        acc[2][2] = __builtin_amdgcn_mfma_f32_16x16x32_f16(a2, b0, acc[2][2], 0, 0, 0);
        acc[3][2] = __builtin_amdgcn_mfma_f32_16x16x32_f16(a3, b0, acc[3][2], 0, 0, 0);
        acc[0][3] = __builtin_amdgcn_mfma_f32_16x16x32_f16(a0, b1, acc[0][3], 0, 0, 0);
        acc[1][3] = __builtin_amdgcn_mfma_f32_16x16x32_f16(a1, b1, acc[1][3], 0, 0, 0);
        acc[2][3] = __builtin_amdgcn_mfma_f32_16x16x32_f16(a2, b1, acc[2][3], 0, 0, 0);
        acc[3][3] = __builtin_amdgcn_mfma_f32_16x16x32_f16(a3, b1, acc[3][3], 0, 0, 0);
        __builtin_amdgcn_s_setprio(0);
        if (t == NT - 1) { VMW(0); } else { VMW(6); }  // gate Q(t,1) for ph2 reads
        __builtin_amdgcn_s_barrier();
        // ---- ph2: ks1, n0/n1 ----
        a0 = *(const f16x8*)(ab + 16384 + aoff[0]);
        a1 = *(const f16x8*)(ab + 16384 + aoff[1]);
        a2 = *(const f16x8*)(ab + 16384 + aoff[2]);
        a3 = *(const f16x8*)(ab + 16384 + aoff[3]);
        b0 = *(const f16x8*)(bb + 8192 + boff[0]);
        b1 = *(const f16x8*)(bb + 8192 + boff[1]);
        if (t + 2 < NT) issue(c, t + 2, 0);  // k-half0 of buf c is dead (drained at ph1)
        __builtin_amdgcn_s_barrier();
        LGKM0;
        __builtin_amdgcn_s_setprio(1);
        acc[0][0] = __builtin_amdgcn_mfma_f32_16x16x32_f16(a0, b0, acc[0][0], 0, 0, 0);
        acc[1][0] = __builtin_amdgcn_mfma_f32_16x16x32_f16(a1, b0, acc[1][0], 0, 0, 0);
        acc[2][0] = __builtin_amdgcn_mfma_f32_16x16x32_f16(a2, b0, acc[2][0], 0, 0, 0);
        acc[3][0] = __builtin_amdgcn_mfma_f32_16x16x32_f16(a3, b0, acc[3][0], 0, 0, 0);
        acc[0][1] = __builtin_amdgcn_mfma_f32_16x16x32_f16(a0, b1, acc[0][1], 0, 0, 0);
        acc[1][1] = __builtin_amdgcn_mfma_f32_16x16x32_f16(a1, b1, acc[1][1], 0, 0, 0);
        acc[2][1] = __builtin_amdgcn_mfma_f32_16x16x32_f16(a2, b1, acc[2][1], 0, 0, 0);
        acc[3][1] = __builtin_amdgcn_mfma_f32_16x16x32_f16(a3, b1, acc[3][1], 0, 0, 0);
        __builtin_amdgcn_s_setprio(0);
        __builtin_amdgcn_s_barrier();
        // ---- ph3: ks1, n2/n3 ----
        b0 = *(const f16x8*)(bb + 8192 + boff[2]);
        b1 = *(const f16x8*)(bb + 8192 + boff[3]);
        __builtin_amdgcn_s_barrier();
        LGKM0;
        __builtin_amdgcn_s_setprio(1);
        acc[0][2] = __builtin_amdgcn_mfma_f32_16x16x32_f16(a0, b0, acc[0][2], 0, 0, 0);
        acc[1][2] = __builtin_amdgcn_mfma_f32_16x16x32_f16(a1, b0, acc[1][2], 0, 0, 0);
        acc[2][2] = __builtin_amdgcn_mfma_f32_16x16x32_f16(a2, b0, acc[2][2], 0, 0, 0);
        acc[3][2] = __builtin_amdgcn_mfma_f32_16x16x32_f16(a3, b0, acc[3][2], 0, 0, 0);
        acc[0][3] = __builtin_amdgcn_mfma_f32_16x16x32_f16(a0, b1, acc[0][3], 0, 0, 0);
        acc[1][3] = __builtin_amdgcn_mfma_f32_16x16x32_f16(a1, b1, acc[1][3], 0, 0, 0);
        acc[2][3] = __builtin_amdgcn_mfma_f32_16x16x32_f16(a2, b1, acc[2][3], 0, 0, 0);
        acc[3][3] = __builtin_amdgcn_mfma_f32_16x16x32_f16(a3, b1, acc[3][3], 0, 0, 0);
        __builtin_amdgcn_s_setprio(0);
        if (t == NT - 2) { VMW(3); } else if (t < NT - 2) { VMW(6); }  // gate Q(t+1,0)
        __builtin_amdgcn_s_barrier();
    }

#pragma unroll
    for (int n = 0; n < 4; ++n) {
        int col = n0 + wn * 64 + n * 16 + lr;
        float bc = bias[col];
#pragma unroll
        for (int m = 0; m < 4; ++m) {
#pragma unroll
            for (int j = 0; j < 4; ++j) {
                int row = m0 + wm * 64 + m * 16 + lq * 4 + j;
                Ch[(size_t)row * N + col] = (f16)(acc[m][n][j] + bc);
            }
        }
    }
}

// ---------------- fp16 MFMA GEMM (sentences): C[M][N] f32 + Ch f16 ----------------
__global__ __launch_bounds__(256) void k_gemm(const f16* __restrict__ A, const f16* __restrict__ Bt,
                                              const float* __restrict__ bias, float* __restrict__ C,
                                              f16* __restrict__ Ch, int M, int N, int K) {
    __shared__ f16 As[128 * 64];
    __shared__ f16 Bs[128 * 64];
    const int tid = threadIdx.x;
    const int lane = tid & 63, wave = tid >> 6;
    const int wr = wave >> 1, wc = wave & 1;
    const int m0 = blockIdx.y * 128, n0 = blockIdx.x * 128;
    const int lr = lane & 15, lq = lane >> 4;
    f32x4 acc[4][4] = {};
    for (int k0 = 0; k0 < K; k0 += 64) {
        __syncthreads();
#pragma unroll
        for (int r = 0; r < 4; ++r) {
            int o = r * 4096 + tid * 16;
            int row = o >> 7;
            int kb = (o & 127) >> 1;
            __builtin_amdgcn_global_load_lds(
                (const __attribute__((address_space(1))) void*)(A + (size_t)(m0 + row) * K + k0 + kb),
                (__attribute__((address_space(3))) void*)((char*)As + o), 16, 0, 0);
        }
#pragma unroll
        for (int r = 0; r < 4; ++r) {
            int o = r * 4096 + tid * 16;
            int row = o >> 7;
            int kb = (o & 127) >> 1;
            __builtin_amdgcn_global_load_lds(
                (const __attribute__((address_space(1))) void*)(Bt + (size_t)(n0 + row) * K + k0 + kb),
                (__attribute__((address_space(3))) void*)((char*)Bs + o), 16, 0, 0);
        }
        __syncthreads();
#pragma unroll
        for (int ks = 0; ks < 2; ++ks) {
            f16x8 af[4], bf[4];
#pragma unroll
            for (int m = 0; m < 4; ++m)
                af[m] = *(const f16x8*)&As[(wr * 64 + m * 16 + lr) * 64 + ks * 32 + lq * 8];
#pragma unroll
            for (int n = 0; n < 4; ++n)
                bf[n] = *(const f16x8*)&Bs[(wc * 64 + n * 16 + lr) * 64 + ks * 32 + lq * 8];
#pragma unroll
            for (int m = 0; m < 4; ++m)
#pragma unroll
                for (int n = 0; n < 4; ++n)
                    acc[m][n] = __builtin_amdgcn_mfma_f32_16x16x32_f16(af[m], bf[n], acc[m][n], 0, 0, 0);
        }
    }
#pragma unroll
    for (int m = 0; m < 4; ++m) {
#pragma unroll
        for (int n = 0; n < 4; ++n) {
            int col = n0 + wc * 64 + n * 16 + lr;
            float bcol = bias[col];
#pragma unroll
            for (int j = 0; j < 4; ++j) {
                int row = m0 + wr * 64 + m * 16 + lq * 4 + j;
                float v = acc[m][n][j] + bcol;
                C[(size_t)row * N + col] = v;
                Ch[(size_t)row * N + col] = (f16)v;
            }
        }
    }
}

// ---------------- ||Sr[b,:,d]|| over L=32 ----------------
__global__ void k_srnorm(const float* __restrict__ Sr, float* __restrict__ SrNorm) {
    int idx = blockIdx.x * 256 + threadIdx.x; // 16384
    int b = idx >> 10, d = idx & 1023;
    float s = 0.f;
#pragma unroll
    for (int l = 0; l < 32; ++l) {
        float v = Sr[((size_t)(b * 32 + l)) * 1024 + d];
        s += v * v;
    }
    SrNorm[idx] = sqrtf(s);
}

// ---------------- per-(b,seg): S = Srh @ Vrh^T (MFMA), softmax stats, W = P @ Vrh ----------------
__global__ __launch_bounds__(256) void k_seg(const f16* __restrict__ Vrh, const f16* __restrict__ Srh,
                                             float* __restrict__ W, float* __restrict__ Mg,
                                             float* __restrict__ Eg) {
    const int b = blockIdx.x >> 4, k = blockIdx.x & 15;
    __shared__ float Sm[32 * 26];
    __shared__ float P[32 * 25];
    __shared__ float VrB[25 * 260];
    const int tid = threadIdx.x;
    const int lane = tid & 63, wave = tid >> 6;
    {
        const int mf = wave >> 1, nf = wave & 1;
        const int lr = lane & 15, lq = lane >> 4;
        f32x4 acc = {};
        const f16* arow = Srh + ((size_t)(b * 32 + mf * 16 + lr)) * 1024 + lq * 8;
        const f16* brow = Vrh + ((size_t)(b * 400 + k * 25 + nf * 16 + lr)) * 1024 + lq * 8;
        for (int k0 = 0; k0 < 1024; k0 += 32) {
            f16x8 a = *(const f16x8*)(arow + k0);
            f16x8 bb = *(const f16x8*)(brow + k0);
            acc = __builtin_amdgcn_mfma_f32_16x16x32_f16(a, bb, acc, 0, 0, 0);
        }
        int t = nf * 16 + lr;
        if (t < 25) {
#pragma unroll
            for (int j = 0; j < 4; ++j) {
                int l = mf * 16 + lq * 4 + j;
                Sm[l * 26 + t] = acc[j];
            }
        }
    }
    __syncthreads();
    if (tid < 32) {
        int l = tid;
        float m = Sm[l * 26];
        for (int t = 1; t < 25; ++t) m = fmaxf(m, Sm[l * 26 + t]);
        float e = 0.f;
        for (int t = 0; t < 25; ++t) {
            float p = __expf(Sm[l * 26 + t] - m);
            P[l * 25 + t] = p;
            e += p;
        }
        Mg[(b * 16 + k) * 32 + l] = m;
        Eg[(b * 16 + k) * 32 + l] = e;
    }
    __syncthreads();
    const int dl = tid & 63, q = tid >> 6;
    for (int c = 0; c < 4; ++c) {
#pragma unroll
        for (int ii = 0; ii < 7; ++ii) {
            int idx4 = tid + ii * 256;
            if (idx4 < 1600) {
                int row = idx4 >> 6, d4 = (idx4 & 63) * 4;
                f16x4 h = *(const f16x4*)&Vrh[((size_t)(b * 400 + k * 25 + row)) * 1024 + c * 256 + d4];
                f32x4 f = { (float)h[0], (float)h[1], (float)h[2], (float)h[3] };
                *(f32x4*)&VrB[row * 260 + d4] = f;
            }
        }
        __syncthreads();
        f32x4 accw[8] = {};
        for (int t = 0; t < 25; ++t) {
            f32x4 v = *(const f32x4*)&VrB[t * 260 + dl * 4];
#pragma unroll
            for (int li = 0; li < 8; ++li) {
                float p = P[(q + li * 4) * 25 + t];
                accw[li][0] += p * v[0];
                accw[li][1] += p * v[1];
                accw[li][2] += p * v[2];
                accw[li][3] += p * v[3];
            }
        }
#pragma unroll
        for (int li = 0; li < 8; ++li) {
            int l = q + li * 4;
            *(f32x4*)&W[(((size_t)(b * 32 + l)) * 16 + k) * 1024 + c * 256 + dl * 4] = accw[li];
        }
        __syncthreads();
    }
}

// ---------------- per-b: EM = exp(M-G), rden, + zero negk (init merged) ----------------
__global__ __launch_bounds__(512) void k_alpha(const float* __restrict__ Mg, const float* __restrict__ Eg,
                                               float* __restrict__ EMg, float* __restrict__ rdeng,
                                               unsigned int* __restrict__ negk) {
    const int b = blockIdx.x;
    __shared__ float EE[32 * 16];
    __shared__ int pS[136], pE[136];
    const int tid = threadIdx.x;
    if (tid == 0) negk[b] = 0u;
    if (tid < 136) {
        int s = 0, rem = tid;
        while (rem >= 16 - s) { rem -= 16 - s; ++s; }
        pS[tid] = s;
        pE[tid] = s + rem;
    }
    if (tid < 32) {
        int l = tid;
        float G = -1e30f;
#pragma unroll
        for (int k = 0; k < 16; ++k) G = fmaxf(G, Mg[(b * 16 + k) * 32 + l]);
#pragma unroll
        for (int k = 0; k < 16; ++k) {
            float em = __expf(Mg[(b * 16 + k) * 32 + l] - G);
            EMg[((size_t)(b * 32 + l)) * 16 + k] = em;
            EE[l * 16 + k] = em * Eg[(b * 16 + k) * 32 + l];
        }
    }
    __syncthreads();
    for (int it = tid; it < 136 * 32; it += 512) {
        int p = it >> 5, l = it & 31;
        float den = 0.f;
        int s = pS[p], e = pE[p];
        for (int k = s; k <= e; ++k) den += EE[l * 16 + k];
        rdeng[((size_t)(b * 136) + p) * 32 + l] = 1.0f / (den + 1e-30f);
    }
}

// ---------------- combine (atomic-free): wave owns s in {w, 15-w}, lane owns d ----------------
__global__ __launch_bounds__(512) void k_combine(const float* __restrict__ W, const float* __restrict__ EMg,
                                                 const float* __restrict__ rdeng, const float* __restrict__ Sr,
                                                 const float* __restrict__ SrNorm, const int* __restrict__ ytrue,
                                                 float* __restrict__ out, unsigned int* __restrict__ negk) {
    extern __shared__ float v_s[]; // [32][16][64] = 32768 floats
    __shared__ float wmax_s[8];
    const int b = blockIdx.x >> 4, dc = blockIdx.x & 15;
    const int tid = threadIdx.x, lane = tid & 63, wave = tid >> 6;
    const int d = dc * 64 + lane;

#pragma unroll 4
    for (int i = 0; i < 64; ++i) {
        int idx = tid + i * 512;
        int l = idx >> 10, k = (idx >> 6) & 15;
        float em = EMg[(b * 32 + l) * 16 + k];
        v_s[idx] = W[(((size_t)(b * 32 + l)) * 16 + k) * 1024 + dc * 64 + (idx & 63)] * em;
    }
    float sr[32];
#pragma unroll
    for (int l = 0; l < 32; ++l) sr[l] = Sr[((size_t)(b * 32 + l)) * 1024 + d];
    const float srn = SrNorm[b * 1024 + d];
    const int sy = ytrue[b * 2], ey = ytrue[b * 2 + 1];
    const int pm = sy * 16 - (sy * (sy - 1)) / 2 + (ey - sy);
    __syncthreads();

    const int sA = wave, sB = 15 - wave;
    const int pA0 = sA * 16 - (sA * (sA - 1)) / 2 - sA;
    const int pB0 = sB * 16 - (sB * (sB - 1)) / 2 - sB;
    float runA[32], runB[32];
#pragma unroll
    for (int l = 0; l < 32; ++l) { runA[l] = 0.f; runB[l] = 0.f; }
    float lmax = -1e30f;

    for (int e = sA; e < 16; ++e) {
        const bool doB = (e >= sB);
        const int pA = pA0 + e, pB = pB0 + e;
        f32x4 rdA[8], rdB[8];
        const float* rA = rdeng + ((size_t)b * 136 + pA) * 32;
        const float* rB = rdeng + ((size_t)b * 136 + pB) * 32;
#pragma unroll
        for (int j = 0; j < 8; ++j) rdA[j] = *(const f32x4*)(rA + j * 4);
        if (doB) {
#pragma unroll
            for (int j = 0; j < 8; ++j) rdB[j] = *(const f32x4*)(rB + j * 4);
        }
        float numA = 0.f, ssqA = 0.f, numB = 0.f, ssqB = 0.f;
#pragma unroll
        for (int l = 0; l < 32; ++l) {
            float ve = v_s[(l * 16 + e) * 64 + lane];
            runA[l] += ve;
            float t = runA[l] * rdA[l >> 2][l & 3];
            numA += t * sr[l];
            ssqA += t * t;
            if (doB) {
                runB[l] += ve;
                float tb = runB[l] * rdB[l >> 2][l & 3];
                numB += tb * sr[l];
                ssqB += tb * tb;
            }
        }
        float scoreA = numA / (sqrtf(ssqA) * srn + 1e-15f);
        if (pA == pm) out[b * 1024 + d] = scoreA;
        else lmax = fmaxf(lmax, scoreA);
        if (doB) {
            float scoreB = numB / (sqrtf(ssqB) * srn + 1e-15f);
            if (pB == pm) out[b * 1024 + d] = scoreB;
            else lmax = fmaxf(lmax, scoreB);
        }
    }
#pragma unroll
    for (int off = 32; off >= 1; off >>= 1) lmax = fmaxf(lmax, __shfl_xor(lmax, off));
    if (lane == 0) wmax_s[wave] = lmax;
    __syncthreads();
    if (tid == 0) {
        float m = wmax_s[0];
#pragma unroll
        for (int w = 1; w < 8; ++w) m = fmaxf(m, wmax_s[w]);
        unsigned u = __float_as_uint(m);
        unsigned key = (u & 0x80000000u) ? ~u : (u | 0x80000000u);
        atomicMax(&negk[b], key);
    }
}

__global__ void k_negout(const unsigned* __restrict__ negk, float* __restrict__ out) {
    int i = threadIdx.x;
    if (i < 16) {
        unsigned key = negk[i];
        unsigned u = (key & 0x80000000u) ? (key ^ 0x80000000u) : ~key;
        out[16384 + i] = __uint_as_float(u);
    }
}

extern "C" void kernel_launch(void* const* d_in, const int* in_sizes, int n_in,
                              void* d_out, int out_size, void* d_ws, size_t ws_size,
                              hipStream_t stream) {
    const float* videos = (const float*)d_in[0];
    const float* sentences = (const float*)d_in[1];
    const float* Wv = (const float*)d_in[2];
    const float* bv = (const float*)d_in[3];
    const float* Ws = (const float*)d_in[4];
    const float* bs = (const float*)d_in[5];
    const int* ytrue = (const int*)d_in[6];
    float* out = (float*)d_out;

    char* ws = (char*)d_ws;
    size_t off = 0;
    auto alloc = [&](size_t bytes) {
        char* p = ws + off;
        off = (off + bytes + 255) & ~(size_t)255;
        return p;
    };
    f16* vh = (f16*)alloc(52428800);      // videos fp16 [6400][4096]
    f16* wvt = (f16*)alloc(8388608);      // Wv^T fp16 [1024][4096]
    f16* sh = (f16*)alloc(786432);        // sentences fp16 [512][768]
    f16* wst = (f16*)alloc(1572864);      // Ws^T fp16 [1024][768]
    f16* Vrh = (f16*)alloc(13107200);     // [6400][1024] f16
    float* Sr = (float*)alloc(2097152);   // [512][1024] f32
    f16* Srh = (f16*)alloc(1048576);      // [512][1024] f16
    float* W = (float*)alloc(33554432);   // [16][32][16][1024] f32
    float* Mg = (float*)alloc(32768);     // [16][16][32]
    float* Eg = (float*)alloc(32768);
    float* EMg = (float*)alloc(32768);    // [16][32][16]
    float* rdeng = (float*)alloc(278528); // [16][136][32]
    float* SrNorm = (float*)alloc(65536); // [16][1024]
    unsigned* negk = (unsigned*)alloc(64);
    if (off > ws_size) return;

    hipLaunchKernelGGL(k_cast, dim3(6553600 / 256), dim3(256), 0, stream, videos, vh, 6553600);
    hipLaunchKernelGGL(k_cast, dim3(98304 / 256), dim3(256), 0, stream, sentences, sh, 98304);
    hipLaunchKernelGGL(k_transpose_cast, dim3(32, 128), dim3(256), 0, stream, Wv, wvt, 4096, 1024);
    hipLaunchKernelGGL(k_transpose_cast, dim3(32, 24), dim3(256), 0, stream, Ws, wst, 768, 1024);
    hipLaunchKernelGGL(k_gemm2, dim3(200), dim3(512), 0, stream, vh, wvt, bv, Vrh);
    hipLaunchKernelGGL(k_gemm, dim3(8, 4), dim3(256), 0, stream, sh, wst, bs, Sr, Srh, 512, 1024, 768);
    hipLaunchKernelGGL(k_srnorm, dim3(64), dim3(256), 0, stream, Sr, SrNorm);
    hipLaunchKernelGGL(k_seg, dim3(256), dim3(256), 0, stream, Vrh, Srh, W, Mg, Eg);
    hipLaunchKernelGGL(k_alpha, dim3(16), dim3(512), 0, stream, Mg, Eg, EMg, rdeng, negk);
    hipLaunchKernelGGL(k_combine, dim3(256), dim3(512), 131072, stream, W, EMg, rdeng, Sr, SrNorm, ytrue, out, negk);
    hipLaunchKernelGGL(k_negout, dim3(1), dim3(64), 0, stream, negk, out);
}

// Round 8
// 329.047 us; speedup vs baseline: 1.0159x; 1.0159x over previous
//
#include <hip/hip_runtime.h>

typedef _Float16 f16;
typedef f16 f16x4 __attribute__((ext_vector_type(4)));
typedef f16 f16x8 __attribute__((ext_vector_type(8)));
typedef float f32x4 __attribute__((ext_vector_type(4)));

// ---------------- merged cast fp32 -> fp16 (videos + sentences) ----------------
__global__ void k_cast2(const float* __restrict__ srcA, f16* __restrict__ dstA, int nA,
                        const float* __restrict__ srcB, f16* __restrict__ dstB, int nB) {
    int i = blockIdx.x * 256 + threadIdx.x;
    const float* s;
    f16* d;
    if (i < nA) {
        s = srcA + (size_t)i * 4;
        d = dstA + (size_t)i * 4;
    } else if (i < nA + nB) {
        int j = i - nA;
        s = srcB + (size_t)j * 4;
        d = dstB + (size_t)j * 4;
    } else {
        return;
    }
    f32x4 v = *(const f32x4*)s;
    f16x4 h = { (f16)v[0], (f16)v[1], (f16)v[2], (f16)v[3] };
    *(f16x4*)d = h;
}

// ---------------- merged transpose+cast: Wv[4096][1024]->wvt, Ws[768][1024]->wst ----------------
__global__ __launch_bounds__(256) void k_tc2(const float* __restrict__ Wv, f16* __restrict__ wvt,
                                             const float* __restrict__ Ws, f16* __restrict__ wst) {
    __shared__ float tile[32 * 33];
    const int C = 1024;
    int y = blockIdx.y;
    const float* src;
    f16* dst;
    int R, r0;
    if (y < 128) { src = Wv; dst = wvt; R = 4096; r0 = y * 32; }
    else { src = Ws; dst = wst; R = 768; r0 = (y - 128) * 32; }
    int tx = threadIdx.x & 31, ty = threadIdx.x >> 5;
    int c0 = blockIdx.x * 32;
#pragma unroll
    for (int i = 0; i < 4; ++i) {
        int r = ty + i * 8;
        tile[r * 33 + tx] = src[(size_t)(r0 + r) * C + c0 + tx];
    }
    __syncthreads();
#pragma unroll
    for (int i = 0; i < 4; ++i) {
        int rr = ty + i * 8;
        dst[(size_t)(c0 + rr) * R + r0 + tx] = (f16)tile[tx * 33 + rr];
    }
}

// ---------------- videos GEMM (R4-measured: 77us, 0 bank conflicts) ----------------
// BM=256 BN=128 BK=64, 512 thr (8 waves 2x4), triple-buffered LDS (144KB), depth-3
// prefetch, counted vmcnt (never 0 in steady state), raw s_barrier,
// swizzle byte^=((lr&7)<<4) pre-applied on global source + swizzled ds_read, setprio.
__global__ __launch_bounds__(512, 2) void k_gemm2(const f16* __restrict__ A, const f16* __restrict__ Bt,
                                                  const float* __restrict__ bias, f16* __restrict__ Ch) {
    constexpr int K = 4096, N = 1024;
    constexpr int BUF = 49152;  // 32KB A + 16KB B per buffer
    __shared__ __attribute__((aligned(16))) char smem[3 * BUF];
    const int tid = threadIdx.x;
    const int lane = tid & 63, wave = tid >> 6;
    const int wm = wave >> 2, wn = wave & 3;
    const int lr = lane & 15, lq = lane >> 4;
    // bijective XCD swizzle: nwg = 200 = 8 * 25
    const int orig = blockIdx.x;
    const int wg = (orig & 7) * 25 + (orig >> 3);
    const int mt = wg >> 3, nt = wg & 7;
    const int m0 = mt * 256, n0 = nt * 128;
    // staging: thread t owns 16B chunk at linear LDS (t + i*512)*16
    // row = (t>>3) + i*64 ; chunk col c = t&7 ; swizzled source col c' = c ^ (row&7)
    const int srow = tid >> 3;
    const int scol = ((tid & 7) ^ ((tid >> 3) & 7)) * 8;  // f16 units
    const f16* aA = A + (size_t)(m0 + srow) * K + scol;
    const f16* aB = Bt + (size_t)(n0 + srow) * K + scol;
    constexpr int NT = K / 64;

    auto stage = [&](int bb, int kt) {
        const f16* a0 = aA + kt * 64;
        const f16* b0 = aB + kt * 64;
        char* la = smem + bb + tid * 16;
#pragma unroll
        for (int i = 0; i < 4; ++i)
            __builtin_amdgcn_global_load_lds(
                (const __attribute__((address_space(1))) void*)(a0 + (size_t)i * 64 * K),
                (__attribute__((address_space(3))) void*)(la + i * 8192), 16, 0, 0);
        char* lb = smem + bb + 32768 + tid * 16;
#pragma unroll
        for (int i = 0; i < 2; ++i)
            __builtin_amdgcn_global_load_lds(
                (const __attribute__((address_space(1))) void*)(b0 + (size_t)i * 64 * K),
                (__attribute__((address_space(3))) void*)(lb + i * 8192), 16, 0, 0);
    };

    f32x4 acc[8][2] = {};
    const int xa = (lr & 7) << 4;

    stage(0, 0);
    stage(BUF, 1);
    stage(2 * BUF, 2);
    asm volatile("s_waitcnt vmcnt(12)" ::: "memory");  // tile 0 landed (tiles 1,2 in flight)
    __builtin_amdgcn_s_barrier();

    int bb = 0;
    for (int t = 0; t < NT; ++t) {
        const char* Ab = smem + bb;
        const char* Bb = smem + bb + 32768;
#pragma unroll
        for (int ks = 0; ks < 2; ++ks) {
            const int co = (ks * 64 + lq * 16) ^ xa;
            f16x8 bf0 = *(const f16x8*)(Bb + (wn * 32 + lr) * 128 + co);
            f16x8 bf1 = *(const f16x8*)(Bb + (wn * 32 + 16 + lr) * 128 + co);
            __builtin_amdgcn_s_setprio(1);
#pragma unroll
            for (int m = 0; m < 8; ++m) {
                f16x8 af = *(const f16x8*)(Ab + (wm * 128 + m * 16 + lr) * 128 + co);
                acc[m][0] = __builtin_amdgcn_mfma_f32_16x16x32_f16(af, bf0, acc[m][0], 0, 0, 0);
                acc[m][1] = __builtin_amdgcn_mfma_f32_16x16x32_f16(af, bf1, acc[m][1], 0, 0, 0);
            }
            __builtin_amdgcn_s_setprio(0);
        }
        __builtin_amdgcn_s_barrier();  // all waves done reading buf bb
        if (t + 3 < NT) {
            stage(bb, t + 3);  // reuse just-freed buffer
            asm volatile("s_waitcnt vmcnt(12)" ::: "memory");  // tile t+1 landed
        } else if (t + 2 < NT) {
            asm volatile("s_waitcnt vmcnt(6)" ::: "memory");
        } else if (t + 1 < NT) {
            asm volatile("s_waitcnt vmcnt(0)" ::: "memory");
        }
        if (t + 1 < NT) {
            __builtin_amdgcn_s_barrier();
            __builtin_amdgcn_sched_barrier(0);
        }
        bb = (bb == 2 * BUF) ? 0 : bb + BUF;
    }

#pragma unroll
    for (int m = 0; m < 8; ++m) {
#pragma unroll
        for (int n = 0; n < 2; ++n) {
            int col = n0 + wn * 32 + n * 16 + lr;
            float bc = bias[col];
#pragma unroll
            for (int j = 0; j < 4; ++j) {
                int row = m0 + wm * 128 + m * 16 + lq * 4 + j;
                Ch[(size_t)row * N + col] = (f16)(acc[m][n][j] + bc);
            }
        }
    }
}

// ---------------- fp16 MFMA GEMM (sentences): C[M][N] f32 + Ch f16 ----------------
__global__ __launch_bounds__(256) void k_gemm(const f16* __restrict__ A, const f16* __restrict__ Bt,
                                              const float* __restrict__ bias, float* __restrict__ C,
                                              f16* __restrict__ Ch, int M, int N, int K) {
    __shared__ f16 As[128 * 64];
    __shared__ f16 Bs[128 * 64];
    const int tid = threadIdx.x;
    const int lane = tid & 63, wave = tid >> 6;
    const int wr = wave >> 1, wc = wave & 1;
    const int m0 = blockIdx.y * 128, n0 = blockIdx.x * 128;
    const int lr = lane & 15, lq = lane >> 4;
    f32x4 acc[4][4] = {};
    for (int k0 = 0; k0 < K; k0 += 64) {
        __syncthreads();
#pragma unroll
        for (int r = 0; r < 4; ++r) {
            int o = r * 4096 + tid * 16;
            int row = o >> 7;
            int kb = (o & 127) >> 1;
            __builtin_amdgcn_global_load_lds(
                (const __attribute__((address_space(1))) void*)(A + (size_t)(m0 + row) * K + k0 + kb),
                (__attribute__((address_space(3))) void*)((char*)As + o), 16, 0, 0);
        }
#pragma unroll
        for (int r = 0; r < 4; ++r) {
            int o = r * 4096 + tid * 16;
            int row = o >> 7;
            int kb = (o & 127) >> 1;
            __builtin_amdgcn_global_load_lds(
                (const __attribute__((address_space(1))) void*)(Bt + (size_t)(n0 + row) * K + k0 + kb),
                (__attribute__((address_space(3))) void*)((char*)Bs + o), 16, 0, 0);
        }
        __syncthreads();
#pragma unroll
        for (int ks = 0; ks < 2; ++ks) {
            f16x8 af[4], bf[4];
#pragma unroll
            for (int m = 0; m < 4; ++m)
                af[m] = *(const f16x8*)&As[(wr * 64 + m * 16 + lr) * 64 + ks * 32 + lq * 8];
#pragma unroll
            for (int n = 0; n < 4; ++n)
                bf[n] = *(const f16x8*)&Bs[(wc * 64 + n * 16 + lr) * 64 + ks * 32 + lq * 8];
#pragma unroll
            for (int m = 0; m < 4; ++m)
#pragma unroll
                for (int n = 0; n < 4; ++n)
                    acc[m][n] = __builtin_amdgcn_mfma_f32_16x16x32_f16(af[m], bf[n], acc[m][n], 0, 0, 0);
        }
    }
#pragma unroll
    for (int m = 0; m < 4; ++m) {
#pragma unroll
        for (int n = 0; n < 4; ++n) {
            int col = n0 + wc * 64 + n * 16 + lr;
            float bcol = bias[col];
#pragma unroll
            for (int j = 0; j < 4; ++j) {
                int row = m0 + wr * 64 + m * 16 + lq * 4 + j;
                float v = acc[m][n][j] + bcol;
                C[(size_t)row * N + col] = v;
                Ch[(size_t)row * N + col] = (f16)v;
            }
        }
    }
}

// ---------------- ||Sr[b,:,d]|| over L=32 ----------------
__global__ void k_srnorm(const float* __restrict__ Sr, float* __restrict__ SrNorm) {
    int idx = blockIdx.x * 256 + threadIdx.x; // 16384
    int b = idx >> 10, d = idx & 1023;
    float s = 0.f;
#pragma unroll
    for (int l = 0; l < 32; ++l) {
        float v = Sr[((size_t)(b * 32 + l)) * 1024 + d];
        s += v * v;
    }
    SrNorm[idx] = sqrtf(s);
}

// ---------------- per-(b,seg): S = Srh @ Vrh^T (MFMA), softmax stats, W = P @ Vrh (W in f16) ----------------
__global__ __launch_bounds__(256) void k_seg(const f16* __restrict__ Vrh, const f16* __restrict__ Srh,
                                             f16* __restrict__ W, float* __restrict__ Mg,
                                             float* __restrict__ Eg) {
    const int b = blockIdx.x >> 4, k = blockIdx.x & 15;
    __shared__ float Sm[32 * 26];
    __shared__ float P[32 * 25];
    __shared__ float VrB[25 * 260];
    const int tid = threadIdx.x;
    const int lane = tid & 63, wave = tid >> 6;
    {
        const int mf = wave >> 1, nf = wave & 1;
        const int lr = lane & 15, lq = lane >> 4;
        f32x4 acc = {};
        const f16* arow = Srh + ((size_t)(b * 32 + mf * 16 + lr)) * 1024 + lq * 8;
        const f16* brow = Vrh + ((size_t)(b * 400 + k * 25 + nf * 16 + lr)) * 1024 + lq * 8;
        for (int k0 = 0; k0 < 1024; k0 += 32) {
            f16x8 a = *(const f16x8*)(arow + k0);
            f16x8 bb = *(const f16x8*)(brow + k0);
            acc = __builtin_amdgcn_mfma_f32_16x16x32_f16(a, bb, acc, 0, 0, 0);
        }
        int t = nf * 16 + lr;
        if (t < 25) {
#pragma unroll
            for (int j = 0; j < 4; ++j) {
                int l = mf * 16 + lq * 4 + j;
                Sm[l * 26 + t] = acc[j];
            }
        }
    }
    __syncthreads();
    if (tid < 32) {
        int l = tid;
        float m = Sm[l * 26];
        for (int t = 1; t < 25; ++t) m = fmaxf(m, Sm[l * 26 + t]);
        float e = 0.f;
        for (int t = 0; t < 25; ++t) {
            float p = __expf(Sm[l * 26 + t] - m);
            P[l * 25 + t] = p;
            e += p;
        }
        Mg[(b * 16 + k) * 32 + l] = m;
        Eg[(b * 16 + k) * 32 + l] = e;
    }
    __syncthreads();
    const int dl = tid & 63, q = tid >> 6;
    for (int c = 0; c < 4; ++c) {
#pragma unroll
        for (int ii = 0; ii < 7; ++ii) {
            int idx4 = tid + ii * 256;
            if (idx4 < 1600) {
                int row = idx4 >> 6, d4 = (idx4 & 63) * 4;
                f16x4 h = *(const f16x4*)&Vrh[((size_t)(b * 400 + k * 25 + row)) * 1024 + c * 256 + d4];
                f32x4 f = { (float)h[0], (float)h[1], (float)h[2], (float)h[3] };
                *(f32x4*)&VrB[row * 260 + d4] = f;
            }
        }
        __syncthreads();
        f32x4 accw[8] = {};
        for (int t = 0; t < 25; ++t) {
            f32x4 v = *(const f32x4*)&VrB[t * 260 + dl * 4];
#pragma unroll
            for (int li = 0; li < 8; ++li) {
                float p = P[(q + li * 4) * 25 + t];
                accw[li][0] += p * v[0];
                accw[li][1] += p * v[1];
                accw[li][2] += p * v[2];
                accw[li][3] += p * v[3];
            }
        }
#pragma unroll
        for (int li = 0; li < 8; ++li) {
            int l = q + li * 4;
            f16x4 h = { (f16)accw[li][0], (f16)accw[li][1], (f16)accw[li][2], (f16)accw[li][3] };
            *(f16x4*)&W[(((size_t)(b * 32 + l)) * 16 + k) * 1024 + c * 256 + dl * 4] = h;
        }
        __syncthreads();
    }
}

// ---------------- per-b: EM = exp(M-G), rden, + zero negk ----------------
__global__ __launch_bounds__(512) void k_alpha(const float* __restrict__ Mg, const float* __restrict__ Eg,
                                               float* __restrict__ EMg, float* __restrict__ rdeng,
                                               unsigned int* __restrict__ negk) {
    const int b = blockIdx.x;
    __shared__ float EE[32 * 16];
    __shared__ int pS[136], pE[136];
    const int tid = threadIdx.x;
    if (tid == 0) negk[b] = 0u;
    if (tid < 136) {
        int s = 0, rem = tid;
        while (rem >= 16 - s) { rem -= 16 - s; ++s; }
        pS[tid] = s;
        pE[tid] = s + rem;
    }
    if (tid < 32) {
        int l = tid;
        float G = -1e30f;
#pragma unroll
        for (int k = 0; k < 16; ++k) G = fmaxf(G, Mg[(b * 16 + k) * 32 + l]);
#pragma unroll
        for (int k = 0; k < 16; ++k) {
            float em = __expf(Mg[(b * 16 + k) * 32 + l] - G);
            EMg[((size_t)(b * 32 + l)) * 16 + k] = em;
            EE[l * 16 + k] = em * Eg[(b * 16 + k) * 32 + l];
        }
    }
    __syncthreads();
    for (int it = tid; it < 136 * 32; it += 512) {
        int p = it >> 5, l = it & 31;
        float den = 0.f;
        int s = pS[p], e = pE[p];
        for (int k = s; k <= e; ++k) den += EE[l * 16 + k];
        rdeng[((size_t)(b * 136) + p) * 32 + l] = 1.0f / (den + 1e-30f);
    }
}

// ---------------- combine (atomic-free): wave owns s in {w, 15-w}, lane owns d ----------------
__global__ __launch_bounds__(512) void k_combine(const f16* __restrict__ W, const float* __restrict__ EMg,
                                                 const float* __restrict__ rdeng, const float* __restrict__ Sr,
                                                 const float* __restrict__ SrNorm, const int* __restrict__ ytrue,
                                                 float* __restrict__ out, unsigned int* __restrict__ negk) {
    extern __shared__ float v_s[]; // [32][16][64] = 32768 floats
    __shared__ float wmax_s[8];
    const int b = blockIdx.x >> 4, dc = blockIdx.x & 15;
    const int tid = threadIdx.x, lane = tid & 63, wave = tid >> 6;
    const int d = dc * 64 + lane;

#pragma unroll 4
    for (int i = 0; i < 64; ++i) {
        int idx = tid + i * 512;
        int l = idx >> 10, k = (idx >> 6) & 15;
        float em = EMg[(b * 32 + l) * 16 + k];
        v_s[idx] = (float)W[(((size_t)(b * 32 + l)) * 16 + k) * 1024 + dc * 64 + (idx & 63)] * em;
    }
    float sr[32];
#pragma unroll
    for (int l = 0; l < 32; ++l) sr[l] = Sr[((size_t)(b * 32 + l)) * 1024 + d];
    const float srn = SrNorm[b * 1024 + d];
    const int sy = ytrue[b * 2], ey = ytrue[b * 2 + 1];
    const int pm = sy * 16 - (sy * (sy - 1)) / 2 + (ey - sy);
    __syncthreads();

    const int sA = wave, sB = 15 - wave;
    const int pA0 = sA * 16 - (sA * (sA - 1)) / 2 - sA;
    const int pB0 = sB * 16 - (sB * (sB - 1)) / 2 - sB;
    float runA[32], runB[32];
#pragma unroll
    for (int l = 0; l < 32; ++l) { runA[l] = 0.f; runB[l] = 0.f; }
    float lmax = -1e30f;

    for (int e = sA; e < 16; ++e) {
        const bool doB = (e >= sB);
        const int pA = pA0 + e, pB = pB0 + e;
        f32x4 rdA[8], rdB[8];
        const float* rA = rdeng + ((size_t)b * 136 + pA) * 32;
        const float* rB = rdeng + ((size_t)b * 136 + pB) * 32;
#pragma unroll
        for (int j = 0; j < 8; ++j) rdA[j] = *(const f32x4*)(rA + j * 4);
        if (doB) {
#pragma unroll
            for (int j = 0; j < 8; ++j) rdB[j] = *(const f32x4*)(rB + j * 4);
        }
        float numA = 0.f, ssqA = 0.f, numB = 0.f, ssqB = 0.f;
#pragma unroll
        for (int l = 0; l < 32; ++l) {
            float ve = v_s[(l * 16 + e) * 64 + lane];
            runA[l] += ve;
            float t = runA[l] * rdA[l >> 2][l & 3];
            numA += t * sr[l];
            ssqA += t * t;
            if (doB) {
                runB[l] += ve;
                float tb = runB[l] * rdB[l >> 2][l & 3];
                numB += tb * sr[l];
                ssqB += tb * tb;
            }
        }
        float scoreA = numA / (sqrtf(ssqA) * srn + 1e-15f);
        if (pA == pm) out[b * 1024 + d] = scoreA;
        else lmax = fmaxf(lmax, scoreA);
        if (doB) {
            float scoreB = numB / (sqrtf(ssqB) * srn + 1e-15f);
            if (pB == pm) out[b * 1024 + d] = scoreB;
            else lmax = fmaxf(lmax, scoreB);
        }
    }
#pragma unroll
    for (int off = 32; off >= 1; off >>= 1) lmax = fmaxf(lmax, __shfl_xor(lmax, off));
    if (lane == 0) wmax_s[wave] = lmax;
    __syncthreads();
    if (tid == 0) {
        float m = wmax_s[0];
#pragma unroll
        for (int w = 1; w < 8; ++w) m = fmaxf(m, wmax_s[w]);
        unsigned u = __float_as_uint(m);
        unsigned key = (u & 0x80000000u) ? ~u : (u | 0x80000000u);
        atomicMax(&negk[b], key);
    }
}

__global__ void k_negout(const unsigned* __restrict__ negk, float* __restrict__ out) {
    int i = threadIdx.x;
    if (i < 16) {
        unsigned key = negk[i];
        unsigned u = (key & 0x80000000u) ? (key ^ 0x80000000u) : ~key;
        out[16384 + i] = __uint_as_float(u);
    }
}

extern "C" void kernel_launch(void* const* d_in, const int* in_sizes, int n_in,
                              void* d_out, int out_size, void* d_ws, size_t ws_size,
                              hipStream_t stream) {
    const float* videos = (const float*)d_in[0];
    const float* sentences = (const float*)d_in[1];
    const float* Wv = (const float*)d_in[2];
    const float* bv = (const float*)d_in[3];
    const float* Ws = (const float*)d_in[4];
    const float* bs = (const float*)d_in[5];
    const int* ytrue = (const int*)d_in[6];
    float* out = (float*)d_out;

    char* ws = (char*)d_ws;
    size_t off = 0;
    auto alloc = [&](size_t bytes) {
        char* p = ws + off;
        off = (off + bytes + 255) & ~(size_t)255;
        return p;
    };
    f16* vh = (f16*)alloc(52428800);      // videos fp16 [6400][4096]
    f16* wvt = (f16*)alloc(8388608);      // Wv^T fp16 [1024][4096]
    f16* sh = (f16*)alloc(786432);        // sentences fp16 [512][768]
    f16* wst = (f16*)alloc(1572864);      // Ws^T fp16 [1024][768]
    f16* Vrh = (f16*)alloc(13107200);     // [6400][1024] f16
    float* Sr = (float*)alloc(2097152);   // [512][1024] f32
    f16* Srh = (f16*)alloc(1048576);      // [512][1024] f16
    f16* W = (f16*)alloc(16777216);       // [16][32][16][1024] f16
    float* Mg = (float*)alloc(32768);     // [16][16][32]
    float* Eg = (float*)alloc(32768);
    float* EMg = (float*)alloc(32768);    // [16][32][16]
    float* rdeng = (float*)alloc(278528); // [16][136][32]
    float* SrNorm = (float*)alloc(65536); // [16][1024]
    unsigned* negk = (unsigned*)alloc(64);
    if (off > ws_size) return;

    // merged casts: videos (6553600 groups) + sentences (98304 groups)
    hipLaunchKernelGGL(k_cast2, dim3((6553600 + 98304 + 255) / 256), dim3(256), 0, stream,
                       videos, vh, 6553600, sentences, sh, 98304);
    // merged transposes: Wv (y<128) + Ws (y>=128)
    hipLaunchKernelGGL(k_tc2, dim3(32, 152), dim3(256), 0, stream, Wv, wvt, Ws, wst);
    hipLaunchKernelGGL(k_gemm2, dim3(200), dim3(512), 0, stream, vh, wvt, bv, Vrh);
    hipLaunchKernelGGL(k_gemm, dim3(8, 4), dim3(256), 0, stream, sh, wst, bs, Sr, Srh, 512, 1024, 768);
    hipLaunchKernelGGL(k_srnorm, dim3(64), dim3(256), 0, stream, Sr, SrNorm);
    hipLaunchKernelGGL(k_seg, dim3(256), dim3(256), 0, stream, Vrh, Srh, W, Mg, Eg);
    hipLaunchKernelGGL(k_alpha, dim3(16), dim3(512), 0, stream, Mg, Eg, EMg, rdeng, negk);
    hipLaunchKernelGGL(k_combine, dim3(256), dim3(512), 131072, stream, W, EMg, rdeng, Sr, SrNorm, ytrue, out, negk);
    hipLaunchKernelGGL(k_negout, dim3(1), dim3(64), 0, stream, negk, out);
}